// Round 2
// baseline (241.125 us; speedup 1.0000x reference)
//
#include <hip/hip_runtime.h>

// One WAVE (64 lanes) per ray-slot; each wave processes 8 rays serially
// (blocked mapping) with software-pipelined global loads. 256-thread block =
// 4 independent waves; grid = N/32 = 2048 blocks = exactly 8 blocks/CU on
// MI355X -> full residency in ONE dispatch round (R5 post-mortem: 16384
// tiny blocks were dispatch-rate-bound at ~11 cy/WG; per-wave work changes
// moved nothing).
//
// Cross-lane ops are all DPP (R5): v_add/mul_f32 row_shr/row_bcast scans,
// wf_sr1 exclusive shift (bitwise-exact neighbor -> the 129-edge interval
// partition stays an exact partition), readlane for the wave total.
// LDS: per-wave ping-pong z-edge rows, ordered by wave-local lgkmcnt only.

constexpr int kT0 = 64;
constexpr int kTF = 128;
constexpr int kWavesPerBlock = 4;
constexpr int kRaysPerWave = 8;    // 2048 blocks, 8/CU -> single-shot residency

// ---- DPP primitives (gfx9/CDNA encodings) -------------------------------
// ROW_SHR|n = 0x110|n, WF_SR1 = 0x138, ROW_BCAST15 = 0x142, ROW_BCAST31 = 0x143
template <int Ctrl, int RowMask>
__device__ __forceinline__ float dpp_mov(float x, float oldv) {
    return __int_as_float(__builtin_amdgcn_update_dpp(
        __float_as_int(oldv), __float_as_int(x), Ctrl, RowMask, 0xf, false));
}

__device__ __forceinline__ float wave_iscan_add(float x) {
    x += dpp_mov<0x111, 0xf>(x, 0.0f);   // row_shr:1
    x += dpp_mov<0x112, 0xf>(x, 0.0f);   // row_shr:2
    x += dpp_mov<0x114, 0xf>(x, 0.0f);   // row_shr:4
    x += dpp_mov<0x118, 0xf>(x, 0.0f);   // row_shr:8
    x += dpp_mov<0x142, 0xa>(x, 0.0f);   // row_bcast15 -> rows 1,3
    x += dpp_mov<0x143, 0xc>(x, 0.0f);   // row_bcast31 -> rows 2,3
    return x;
}

__device__ __forceinline__ float wave_iscan_mul(float x) {
    x *= dpp_mov<0x111, 0xf>(x, 1.0f);
    x *= dpp_mov<0x112, 0xf>(x, 1.0f);
    x *= dpp_mov<0x114, 0xf>(x, 1.0f);
    x *= dpp_mov<0x118, 0xf>(x, 1.0f);
    x *= dpp_mov<0x142, 0xa>(x, 1.0f);
    x *= dpp_mov<0x143, 0xc>(x, 1.0f);
    return x;
}

__device__ __forceinline__ float wave_shr1(float x, float oldv) {
    return dpp_mov<0x138, 0xf>(x, oldv);  // wf_sr1
}

// ---- per-ray input bundle (prefetched one ray ahead) --------------------
struct RayIn {
    float ox, oy, oz, dx, dy, dz;   // ray origin / direction (wave-uniform value)
    float wraw;                     // coarse weight, lane's interval
    float2 sg;                      // sigmas[2*lane], [2*lane+1]
    float2 rgA, rgB, rgC;           // rgbs[6*lane .. 6*lane+5]
};

__device__ __forceinline__ RayIn load_ray(const float* __restrict__ rays_o,
                                          const float* __restrict__ rays_d,
                                          const float* __restrict__ weights,
                                          const float* __restrict__ sigmas,
                                          const float* __restrict__ rgbs,
                                          int ray, int lane) {
    RayIn r;
    r.ox = rays_o[ray * 3 + 0]; r.oy = rays_o[ray * 3 + 1]; r.oz = rays_o[ray * 3 + 2];
    r.dx = rays_d[ray * 3 + 0]; r.dy = rays_d[ray * 3 + 1]; r.dz = rays_d[ray * 3 + 2];
    r.wraw = weights[(size_t)ray * kT0 + lane];
    r.sg = *(const float2*)(sigmas + (size_t)ray * kTF + 2 * lane);
    const float* rgb_row = rgbs + (size_t)ray * (kTF * 3) + 6 * lane;  // 8B-aligned
    r.rgA = *(const float2*)(rgb_row + 0);
    r.rgB = *(const float2*)(rgb_row + 2);
    r.rgC = *(const float2*)(rgb_row + 4);
    return r;
}

__device__ __forceinline__ void process_ray(const RayIn& rin, int ray, int lane,
                                            float a0, float a1, float a2,
                                            float a3, float a4, float a5,
                                            float* __restrict__ zrow,
                                            float* __restrict__ out) {
    // ---- ray-AABB near/far ----
    float near, far;
    {
        const float rx = __builtin_amdgcn_rcpf(rin.dx + 1e-15f);
        const float ry = __builtin_amdgcn_rcpf(rin.dy + 1e-15f);
        const float rz = __builtin_amdgcn_rcpf(rin.dz + 1e-15f);
        const float t0x = (a0 - rin.ox) * rx, t1x = (a3 - rin.ox) * rx;
        const float t0y = (a1 - rin.oy) * ry, t1y = (a4 - rin.oy) * ry;
        const float t0z = (a2 - rin.oz) * rz, t1z = (a5 - rin.oz) * rz;
        near = fmaxf(fmaxf(fminf(t0x, t1x), fminf(t0y, t1y)), fminf(t0z, t1z));
        far  = fminf(fminf(fmaxf(t0x, t1x), fmaxf(t0y, t1y)), fmaxf(t0z, t1z));
        if (far < near) { near = 1e9f; far = 1e9f; }
        near = fmaxf(near, 0.05f);
    }
    const float range = far - near;

    // ---- CDF inclusive scan over coarse weights (DPP) ----
    const float scan  = wave_iscan_add(rin.wraw + 0.01f);
    const float total = __int_as_float(__builtin_amdgcn_readlane(__float_as_int(scan), 63));
    const float c_hi  = fminf(scan * __builtin_amdgcn_rcpf(total), 1.0f); // cdf[lane+1]
    const float c_lo  = wave_shr1(c_hi, 0.0f);                            // cdf[lane]

    // ---- interval-owner scatter of the 129 fine bin edges ----
    {
        const float b_lo = near + range * ((float)lane * (1.0f / kT0));
        const float bw = range * (1.0f / kT0);
        int j_start = (int)ceilf(fmaf(129.0f, c_lo, -0.5f));
        int j_end   = (int)ceilf(fmaf(129.0f, c_hi, -0.5f));
        j_start = j_start < 0 ? 0 : j_start;
        j_end   = j_end > (kTF + 1) ? (kTF + 1) : j_end;
        const float rdenom = __builtin_amdgcn_rcpf(c_hi - c_lo);
        float fj = (float)j_start + 0.5f;
        for (int j = j_start; j < j_end; ++j, fj += 1.0f) {
            const float u = fj * (1.0f / 129.0f);
            float t = (u - c_lo) * rdenom;
            t = fminf(fmaxf(t, 0.0f), 1.0f);
            zrow[j] = fmaf(t, bw, b_lo);
        }
    }
    // wave-local LDS ordering: this wave's ds_writes drained before its reads.
    __builtin_amdgcn_wave_barrier();
    __asm__ volatile("s_waitcnt lgkmcnt(0)" ::: "memory");
    __builtin_amdgcn_wave_barrier();

    // ---- per-lane fine samples 2*lane, 2*lane+1 ----
    const float2 ze01 = *(const float2*)&zrow[2 * lane];   // 8B-aligned (row=130)
    const float  ze2  = zrow[2 * lane + 2];
    const float d0 = ze01.y - ze01.x, d1 = ze2 - ze01.y;
    const float z0 = 0.5f * (ze01.x + ze01.y), z1 = 0.5f * (ze01.y + ze2);

    const float e0 = __expf(-rin.sg.x * d0);
    const float e1 = __expf(-rin.sg.y * d1);
    const float alpha0 = 1.0f - e0, alpha1 = 1.0f - e1;
    const float f0 = e0 + 1e-10f;
    const float f1 = e1 + 1e-10f;

    // ---- transmittance: wave64 product scan + exact exclusive shift ----
    const float ps   = wave_iscan_mul(f0 * f1);
    const float excl = wave_shr1(ps, 1.0f);
    const float w0 = alpha0 * excl;
    const float w1 = alpha1 * excl * f0;

    // ---- image/depth: 4 DPP scan-reductions; lane 63 holds totals ----
    float vr = wave_iscan_add(w0 * rin.rgA.x + w1 * rin.rgB.y);
    float vg = wave_iscan_add(w0 * rin.rgA.y + w1 * rin.rgC.x);
    float vb = wave_iscan_add(w0 * rin.rgB.x + w1 * rin.rgC.y);
    float vd = wave_iscan_add(w0 * z0 + w1 * z1);

    float* orow = out + (size_t)ray * (4 + kTF * 3);   // 16B-aligned (388*4=1552)
    if (lane == 63) {
        *(float4*)orow = make_float4(vr, vg, vb, vd);
    }

    // ---- contraction (branchless) + dwordx2 stores ----
    float oxyz[6];
    #pragma unroll
    for (int s = 0; s < 2; ++s) {
        const float z = s ? z1 : z0;
        float px = rin.ox + rin.dx * z;
        float py = rin.oy + rin.dy * z;
        float pz = rin.oz + rin.dz * z;
        const float ax = fabsf(px), ay = fabsf(py), az = fabsf(pz);
        float mag; int idx;
        if (ax >= ay && ax >= az) { mag = ax; idx = 0; }
        else if (ay >= az)        { mag = ay; idx = 1; }
        else                      { mag = az; idx = 2; }
        const float inv    = __builtin_amdgcn_rcpf(mag);
        const bool  inside = mag < 1.0f;
        const float s_oth  = inside ? 1.0f : inv;
        const float s_max  = inside ? 1.0f : (2.0f - inv) * inv;
        oxyz[3 * s + 0] = px * ((idx == 0) ? s_max : s_oth);
        oxyz[3 * s + 1] = py * ((idx == 1) ? s_max : s_oth);
        oxyz[3 * s + 2] = pz * ((idx == 2) ? s_max : s_oth);
    }
    float* o = orow + 4 + 6 * lane;                    // 8B-aligned
    *(float2*)(o + 0) = make_float2(oxyz[0], oxyz[1]);
    *(float2*)(o + 2) = make_float2(oxyz[2], oxyz[3]);
    *(float2*)(o + 4) = make_float2(oxyz[4], oxyz[5]);
}

// 2nd launch_bounds arg = min waves per EU: 8 -> VGPR cap 64, keeps all
// 32 waves/CU resident despite the double-buffered ray state.
__global__ __launch_bounds__(256, 8)
void nerf_render_kernel(const float* __restrict__ rays_o,
                        const float* __restrict__ rays_d,
                        const float* __restrict__ aabb,
                        const float* __restrict__ weights,   // [N, 64]
                        const float* __restrict__ sigmas,    // [N, 128]
                        const float* __restrict__ rgbs,      // [N, 128, 3]
                        float* __restrict__ out)             // [N, 388]
{
    const int lane = threadIdx.x & 63;
    const int wid  = threadIdx.x >> 6;
    const int gw   = blockIdx.x * kWavesPerBlock + wid;   // global wave id
    const int ray0 = gw * kRaysPerWave;                   // blocked mapping

    // ping-pong z-edge rows: WAR-free across pipeline iterations
    __shared__ float s_zedge[2][kWavesPerBlock][kTF + 2];   // rows padded to 130

    // aabb is identical for all rays: load once
    const float a0 = aabb[0], a1 = aabb[1], a2 = aabb[2];
    const float a3 = aabb[3], a4 = aabb[4], a5 = aabb[5];

    RayIn cur = load_ray(rays_o, rays_d, weights, sigmas, rgbs, ray0, lane);

    #pragma unroll
    for (int t = 0; t < kRaysPerWave; ++t) {
        RayIn nxt;
        if (t + 1 < kRaysPerWave) {
            // issue next ray's global loads before this ray's compute:
            // HBM/LLC latency hides under ~2000 cy of DPP/VALU work.
            nxt = load_ray(rays_o, rays_d, weights, sigmas, rgbs, ray0 + t + 1, lane);
        }
        process_ray(cur, ray0 + t, lane, a0, a1, a2, a3, a4, a5,
                    &s_zedge[t & 1][wid][0], out);
        cur = nxt;
    }
}

extern "C" void kernel_launch(void* const* d_in, const int* in_sizes, int n_in,
                              void* d_out, int out_size, void* d_ws, size_t ws_size,
                              hipStream_t stream) {
    const float* rays_o  = (const float*)d_in[0];
    const float* rays_d  = (const float*)d_in[1];
    const float* aabb    = (const float*)d_in[2];
    const float* weights = (const float*)d_in[3];
    const float* sigmas  = (const float*)d_in[4];
    const float* rgbs    = (const float*)d_in[5];
    float* out           = (float*)d_out;

    const int N = in_sizes[0] / 3;   // rays_o is [N,3]
    const int blocks = N / (kWavesPerBlock * kRaysPerWave);   // N=65536 -> 2048
    nerf_render_kernel<<<blocks, 256, 0, stream>>>(rays_o, rays_d, aabb, weights, sigmas, rgbs, out);
}

// Round 3
// 222.867 us; speedup vs baseline: 1.0819x; 1.0819x over previous
//
#include <hip/hip_runtime.h>

// One WAVE (64 lanes) processes TWO independent rays (A, B) with all global
// loads for both issued at wave entry. R4/R5/R6 were all pinned at effective
// ~2.4 TB/s = bytes_in_flight / latency (Little's law): ~2.3 KB outstanding
// per wave x 23 resident waves/CU was the cap. Doubling per-wave in-flight
// bytes with two fully-independent interleaved compute chains is the lever;
// wave count itself is capped at 32/CU.
//
// Ray pairing (gw, gw + N/2): concurrent waves stay on ADJACENT rays in two
// contiguous frontiers (R6's blocked mapping cost +36% HBM bytes; avoid).
//
// Cross-lane ops all DPP (R5): row_shr/row_bcast scans, wf_sr1 exclusive
// shift (bitwise-exact neighbor -> 129-edge interval partition stays exact),
// readlane for the wave total. LDS: per-wave z-edge rows, wave-local lgkmcnt.

constexpr int kT0 = 64;
constexpr int kTF = 128;
constexpr int kWavesPerBlock = 4;

// ---- DPP primitives (gfx9/CDNA encodings) -------------------------------
// ROW_SHR|n = 0x110|n, WF_SR1 = 0x138, ROW_BCAST15 = 0x142, ROW_BCAST31 = 0x143
template <int Ctrl, int RowMask>
__device__ __forceinline__ float dpp_mov(float x, float oldv) {
    return __int_as_float(__builtin_amdgcn_update_dpp(
        __float_as_int(oldv), __float_as_int(x), Ctrl, RowMask, 0xf, false));
}

// two interleaved inclusive sum scans (independent chains -> dual-issue room)
__device__ __forceinline__ void wave_iscan_add2(float& a, float& b) {
    a += dpp_mov<0x111, 0xf>(a, 0.0f);  b += dpp_mov<0x111, 0xf>(b, 0.0f);
    a += dpp_mov<0x112, 0xf>(a, 0.0f);  b += dpp_mov<0x112, 0xf>(b, 0.0f);
    a += dpp_mov<0x114, 0xf>(a, 0.0f);  b += dpp_mov<0x114, 0xf>(b, 0.0f);
    a += dpp_mov<0x118, 0xf>(a, 0.0f);  b += dpp_mov<0x118, 0xf>(b, 0.0f);
    a += dpp_mov<0x142, 0xa>(a, 0.0f);  b += dpp_mov<0x142, 0xa>(b, 0.0f);
    a += dpp_mov<0x143, 0xc>(a, 0.0f);  b += dpp_mov<0x143, 0xc>(b, 0.0f);
}

__device__ __forceinline__ void wave_iscan_mul2(float& a, float& b) {
    a *= dpp_mov<0x111, 0xf>(a, 1.0f);  b *= dpp_mov<0x111, 0xf>(b, 1.0f);
    a *= dpp_mov<0x112, 0xf>(a, 1.0f);  b *= dpp_mov<0x112, 0xf>(b, 1.0f);
    a *= dpp_mov<0x114, 0xf>(a, 1.0f);  b *= dpp_mov<0x114, 0xf>(b, 1.0f);
    a *= dpp_mov<0x118, 0xf>(a, 1.0f);  b *= dpp_mov<0x118, 0xf>(b, 1.0f);
    a *= dpp_mov<0x142, 0xa>(a, 1.0f);  b *= dpp_mov<0x142, 0xa>(b, 1.0f);
    a *= dpp_mov<0x143, 0xc>(a, 1.0f);  b *= dpp_mov<0x143, 0xc>(b, 1.0f);
}

__device__ __forceinline__ float wave_iscan_add(float x) {
    x += dpp_mov<0x111, 0xf>(x, 0.0f);
    x += dpp_mov<0x112, 0xf>(x, 0.0f);
    x += dpp_mov<0x114, 0xf>(x, 0.0f);
    x += dpp_mov<0x118, 0xf>(x, 0.0f);
    x += dpp_mov<0x142, 0xa>(x, 0.0f);
    x += dpp_mov<0x143, 0xc>(x, 0.0f);
    return x;
}

__device__ __forceinline__ float wave_shr1(float x, float oldv) {
    return dpp_mov<0x138, 0xf>(x, oldv);  // wf_sr1
}

// min waves/EU = 8 -> VGPR cap 64 -> full 32 waves/CU residency with 2-ray state
__global__ __launch_bounds__(256, 8)
void nerf_render_kernel(const float* __restrict__ rays_o,
                        const float* __restrict__ rays_d,
                        const float* __restrict__ aabb,
                        const float* __restrict__ weights,   // [N, 64]
                        const float* __restrict__ sigmas,    // [N, 128]
                        const float* __restrict__ rgbs,      // [N, 128, 3]
                        float* __restrict__ out,             // [N, 388]
                        int Nh)                              // N/2
{
    const int lane = threadIdx.x & 63;
    const int wid  = threadIdx.x >> 6;
    const int gw   = blockIdx.x * kWavesPerBlock + wid;
    const int rayA = gw;
    const int rayB = gw + Nh;

    __shared__ float s_zedge[kWavesPerBlock][2][kTF + 2];   // 130-float rows, 8B-aligned

    // ---- issue ALL global loads for BOTH rays up front (consume order) ----
    const float oxA = rays_o[rayA * 3 + 0], oyA = rays_o[rayA * 3 + 1], ozA = rays_o[rayA * 3 + 2];
    const float dxA = rays_d[rayA * 3 + 0], dyA = rays_d[rayA * 3 + 1], dzA = rays_d[rayA * 3 + 2];
    const float oxB = rays_o[rayB * 3 + 0], oyB = rays_o[rayB * 3 + 1], ozB = rays_o[rayB * 3 + 2];
    const float dxB = rays_d[rayB * 3 + 0], dyB = rays_d[rayB * 3 + 1], dzB = rays_d[rayB * 3 + 2];
    const float wrawA = weights[(size_t)rayA * kT0 + lane];
    const float wrawB = weights[(size_t)rayB * kT0 + lane];
    const float2 sgA = *(const float2*)(sigmas + (size_t)rayA * kTF + 2 * lane);
    const float2 sgB = *(const float2*)(sigmas + (size_t)rayB * kTF + 2 * lane);
    const float* rgbA = rgbs + (size_t)rayA * (kTF * 3) + 6 * lane;  // 8B-aligned
    const float* rgbB = rgbs + (size_t)rayB * (kTF * 3) + 6 * lane;
    const float2 rgA0 = *(const float2*)(rgbA + 0);
    const float2 rgA1 = *(const float2*)(rgbA + 2);
    const float2 rgA2 = *(const float2*)(rgbA + 4);
    const float2 rgB0 = *(const float2*)(rgbB + 0);
    const float2 rgB1 = *(const float2*)(rgbB + 2);
    const float2 rgB2 = *(const float2*)(rgbB + 4);

    const float a0 = aabb[0], a1 = aabb[1], a2 = aabb[2];
    const float a3 = aabb[3], a4 = aabb[4], a5 = aabb[5];

    // ---- ray-AABB near/far, both rays ----
    float nearA, farA, nearB, farB;
    {
        const float rx = __builtin_amdgcn_rcpf(dxA + 1e-15f);
        const float ry = __builtin_amdgcn_rcpf(dyA + 1e-15f);
        const float rz = __builtin_amdgcn_rcpf(dzA + 1e-15f);
        const float t0x = (a0 - oxA) * rx, t1x = (a3 - oxA) * rx;
        const float t0y = (a1 - oyA) * ry, t1y = (a4 - oyA) * ry;
        const float t0z = (a2 - ozA) * rz, t1z = (a5 - ozA) * rz;
        nearA = fmaxf(fmaxf(fminf(t0x, t1x), fminf(t0y, t1y)), fminf(t0z, t1z));
        farA  = fminf(fminf(fmaxf(t0x, t1x), fmaxf(t0y, t1y)), fmaxf(t0z, t1z));
        if (farA < nearA) { nearA = 1e9f; farA = 1e9f; }
        nearA = fmaxf(nearA, 0.05f);
    }
    {
        const float rx = __builtin_amdgcn_rcpf(dxB + 1e-15f);
        const float ry = __builtin_amdgcn_rcpf(dyB + 1e-15f);
        const float rz = __builtin_amdgcn_rcpf(dzB + 1e-15f);
        const float t0x = (a0 - oxB) * rx, t1x = (a3 - oxB) * rx;
        const float t0y = (a1 - oyB) * ry, t1y = (a4 - oyB) * ry;
        const float t0z = (a2 - ozB) * rz, t1z = (a5 - ozB) * rz;
        nearB = fmaxf(fmaxf(fminf(t0x, t1x), fminf(t0y, t1y)), fminf(t0z, t1z));
        farB  = fminf(fminf(fmaxf(t0x, t1x), fmaxf(t0y, t1y)), fmaxf(t0z, t1z));
        if (farB < nearB) { nearB = 1e9f; farB = 1e9f; }
        nearB = fmaxf(nearB, 0.05f);
    }
    const float rangeA = farA - nearA;
    const float rangeB = farB - nearB;

    // ---- CDF inclusive scans (interleaved DPP chains) ----
    float scanA = wrawA + 0.01f, scanB = wrawB + 0.01f;
    wave_iscan_add2(scanA, scanB);
    const float totA = __int_as_float(__builtin_amdgcn_readlane(__float_as_int(scanA), 63));
    const float totB = __int_as_float(__builtin_amdgcn_readlane(__float_as_int(scanB), 63));
    const float c_hiA = fminf(scanA * __builtin_amdgcn_rcpf(totA), 1.0f);
    const float c_hiB = fminf(scanB * __builtin_amdgcn_rcpf(totB), 1.0f);
    const float c_loA = wave_shr1(c_hiA, 0.0f);
    const float c_loB = wave_shr1(c_hiB, 0.0f);

    // ---- interval-owner scatter of 129 fine bin edges, both rays ----
    {
        const float b_lo = nearA + rangeA * ((float)lane * (1.0f / kT0));
        const float bw = rangeA * (1.0f / kT0);
        int j_start = (int)ceilf(fmaf(129.0f, c_loA, -0.5f));
        int j_end   = (int)ceilf(fmaf(129.0f, c_hiA, -0.5f));
        j_start = j_start < 0 ? 0 : j_start;
        j_end   = j_end > (kTF + 1) ? (kTF + 1) : j_end;
        const float rdenom = __builtin_amdgcn_rcpf(c_hiA - c_loA);
        float fj = (float)j_start + 0.5f;
        for (int j = j_start; j < j_end; ++j, fj += 1.0f) {
            float t = (fj * (1.0f / 129.0f) - c_loA) * rdenom;
            t = fminf(fmaxf(t, 0.0f), 1.0f);
            s_zedge[wid][0][j] = fmaf(t, bw, b_lo);
        }
    }
    {
        const float b_lo = nearB + rangeB * ((float)lane * (1.0f / kT0));
        const float bw = rangeB * (1.0f / kT0);
        int j_start = (int)ceilf(fmaf(129.0f, c_loB, -0.5f));
        int j_end   = (int)ceilf(fmaf(129.0f, c_hiB, -0.5f));
        j_start = j_start < 0 ? 0 : j_start;
        j_end   = j_end > (kTF + 1) ? (kTF + 1) : j_end;
        const float rdenom = __builtin_amdgcn_rcpf(c_hiB - c_loB);
        float fj = (float)j_start + 0.5f;
        for (int j = j_start; j < j_end; ++j, fj += 1.0f) {
            float t = (fj * (1.0f / 129.0f) - c_loB) * rdenom;
            t = fminf(fmaxf(t, 0.0f), 1.0f);
            s_zedge[wid][1][j] = fmaf(t, bw, b_lo);
        }
    }
    // wave-local LDS ordering (rows touched by this wave only)
    __builtin_amdgcn_wave_barrier();
    __asm__ volatile("s_waitcnt lgkmcnt(0)" ::: "memory");
    __builtin_amdgcn_wave_barrier();

    // ---- per-lane fine samples 2*lane, 2*lane+1, both rays ----
    const float2 zeA01 = *(const float2*)&s_zedge[wid][0][2 * lane];
    const float  zeA2  = s_zedge[wid][0][2 * lane + 2];
    const float2 zeB01 = *(const float2*)&s_zedge[wid][1][2 * lane];
    const float  zeB2  = s_zedge[wid][1][2 * lane + 2];
    const float d0A = zeA01.y - zeA01.x, d1A = zeA2 - zeA01.y;
    const float z0A = 0.5f * (zeA01.x + zeA01.y), z1A = 0.5f * (zeA01.y + zeA2);
    const float d0B = zeB01.y - zeB01.x, d1B = zeB2 - zeB01.y;
    const float z0B = 0.5f * (zeB01.x + zeB01.y), z1B = 0.5f * (zeB01.y + zeB2);

    const float e0A = __expf(-sgA.x * d0A), e1A = __expf(-sgA.y * d1A);
    const float e0B = __expf(-sgB.x * d0B), e1B = __expf(-sgB.y * d1B);
    const float al0A = 1.0f - e0A, al1A = 1.0f - e1A;
    const float al0B = 1.0f - e0B, al1B = 1.0f - e1B;
    const float f0A = e0A + 1e-10f, f1A = e1A + 1e-10f;
    const float f0B = e0B + 1e-10f, f1B = e1B + 1e-10f;

    // ---- transmittance product scans (interleaved) + exact exclusive shift ----
    float psA = f0A * f1A, psB = f0B * f1B;
    wave_iscan_mul2(psA, psB);
    const float exclA = wave_shr1(psA, 1.0f);
    const float exclB = wave_shr1(psB, 1.0f);
    const float w0A = al0A * exclA, w1A = al1A * exclA * f0A;
    const float w0B = al0B * exclB, w1B = al1B * exclB * f0B;

    // ---- image/depth reductions (8 independent DPP chains) ----
    float vrA = w0A * rgA0.x + w1A * rgA1.y;
    float vgA = w0A * rgA0.y + w1A * rgA2.x;
    float vbA = w0A * rgA1.x + w1A * rgA2.y;
    float vdA = w0A * z0A + w1A * z1A;
    float vrB = w0B * rgB0.x + w1B * rgB1.y;
    float vgB = w0B * rgB0.y + w1B * rgB2.x;
    float vbB = w0B * rgB1.x + w1B * rgB2.y;
    float vdB = w0B * z0B + w1B * z1B;
    wave_iscan_add2(vrA, vrB);
    wave_iscan_add2(vgA, vgB);
    wave_iscan_add2(vbA, vbB);
    wave_iscan_add2(vdA, vdB);

    float* orowA = out + (size_t)rayA * (4 + kTF * 3);   // 1552 B rows, 16B-aligned
    float* orowB = out + (size_t)rayB * (4 + kTF * 3);
    if (lane == 63) {
        *(float4*)orowA = make_float4(vrA, vgA, vbA, vdA);
        *(float4*)orowB = make_float4(vrB, vgB, vbB, vdB);
    }

    // ---- contraction (branchless) + dwordx2 stores, both rays ----
    #pragma unroll
    for (int r = 0; r < 2; ++r) {
        const float ox = r ? oxB : oxA, oy = r ? oyB : oyA, oz = r ? ozB : ozA;
        const float dx = r ? dxB : dxA, dy = r ? dyB : dyA, dz = r ? dzB : dzA;
        const float z0 = r ? z0B : z0A, z1 = r ? z1B : z1A;
        float oxyz[6];
        #pragma unroll
        for (int s = 0; s < 2; ++s) {
            const float z = s ? z1 : z0;
            float px = ox + dx * z;
            float py = oy + dy * z;
            float pz = oz + dz * z;
            const float ax = fabsf(px), ay = fabsf(py), az = fabsf(pz);
            float mag; int idx;
            if (ax >= ay && ax >= az) { mag = ax; idx = 0; }
            else if (ay >= az)        { mag = ay; idx = 1; }
            else                      { mag = az; idx = 2; }
            const float inv    = __builtin_amdgcn_rcpf(mag);
            const bool  inside = mag < 1.0f;
            const float s_oth  = inside ? 1.0f : inv;
            const float s_max  = inside ? 1.0f : (2.0f - inv) * inv;
            oxyz[3 * s + 0] = px * ((idx == 0) ? s_max : s_oth);
            oxyz[3 * s + 1] = py * ((idx == 1) ? s_max : s_oth);
            oxyz[3 * s + 2] = pz * ((idx == 2) ? s_max : s_oth);
        }
        float* o = (r ? orowB : orowA) + 4 + 6 * lane;   // 8B-aligned
        *(float2*)(o + 0) = make_float2(oxyz[0], oxyz[1]);
        *(float2*)(o + 2) = make_float2(oxyz[2], oxyz[3]);
        *(float2*)(o + 4) = make_float2(oxyz[4], oxyz[5]);
    }
}

extern "C" void kernel_launch(void* const* d_in, const int* in_sizes, int n_in,
                              void* d_out, int out_size, void* d_ws, size_t ws_size,
                              hipStream_t stream) {
    const float* rays_o  = (const float*)d_in[0];
    const float* rays_d  = (const float*)d_in[1];
    const float* aabb    = (const float*)d_in[2];
    const float* weights = (const float*)d_in[3];
    const float* sigmas  = (const float*)d_in[4];
    const float* rgbs    = (const float*)d_in[5];
    float* out           = (float*)d_out;

    const int N = in_sizes[0] / 3;   // rays_o is [N,3]
    const int Nh = N / 2;
    const int blocks = Nh / kWavesPerBlock;   // N=65536 -> 8192 blocks
    nerf_render_kernel<<<blocks, 256, 0, stream>>>(rays_o, rays_d, aabb, weights, sigmas, rgbs, out, Nh);
}

// Round 6
// 220.630 us; speedup vs baseline: 1.0929x; 1.0101x over previous
//
#include <hip/hip_runtime.h>

// One WAVE (64 lanes) per ray. R10: coalesce the two dominant 100-MB streams.
//
// R4-R7 all pinned at ~2.4 TB/s effective HBM BW. Shared property: rgb reads
// and xyz writes use 24 B/lane (3x float2 at stride 24) -> each instruction
// touches ALL 24 cache lines of the 1536 B row partially; 3 instructions
// re-touch the same lines = 3x line-request amplification on ~200 MB of
// traffic. R10 stages both streams through LDS so every global access is a
// contiguous 512 B/instruction:
//   rgb:  3x coalesced float2 loads (base + 2*lane + 128k) -> LDS -> 24 B/lane
//   xyz:  24 B/lane -> LDS -> 3x coalesced float2 stores
// Byte counts unchanged; request count on the big streams drops 3x.
// (R9's nt stores REMOVED: they corrupted graph-replay readback. No pin.)
//
// Cross-lane ops all DPP: row_shr/row_bcast scans, wf_sr1 exclusive shift
// (bitwise-exact neighbor -> 129-edge interval partition stays exact),
// readlane for wave total. All LDS is per-wave; wave-local lgkmcnt ordering
// only, no block barriers.

constexpr int kT0 = 64;
constexpr int kTF = 128;
constexpr int kWavesPerBlock = 4;

// per-wave LDS: [0..129] z-edges (pad to 132 for 8B align), [132..516) stage
constexpr int kZPad  = 132;
constexpr int kStage = 384;
constexpr int kWaveLds = kZPad + kStage + 4;   // 520 floats -> 2080 B, 8B-aligned rows

// ---- DPP primitives (gfx9/CDNA encodings) -------------------------------
// ROW_SHR|n = 0x110|n, WF_SR1 = 0x138, ROW_BCAST15 = 0x142, ROW_BCAST31 = 0x143
template <int Ctrl, int RowMask>
__device__ __forceinline__ float dpp_mov(float x, float oldv) {
    return __int_as_float(__builtin_amdgcn_update_dpp(
        __float_as_int(oldv), __float_as_int(x), Ctrl, RowMask, 0xf, false));
}

__device__ __forceinline__ float wave_iscan_add(float x) {
    x += dpp_mov<0x111, 0xf>(x, 0.0f);   // row_shr:1
    x += dpp_mov<0x112, 0xf>(x, 0.0f);   // row_shr:2
    x += dpp_mov<0x114, 0xf>(x, 0.0f);   // row_shr:4
    x += dpp_mov<0x118, 0xf>(x, 0.0f);   // row_shr:8
    x += dpp_mov<0x142, 0xa>(x, 0.0f);   // row_bcast15 -> rows 1,3
    x += dpp_mov<0x143, 0xc>(x, 0.0f);   // row_bcast31 -> rows 2,3
    return x;
}

__device__ __forceinline__ float wave_iscan_mul(float x) {
    x *= dpp_mov<0x111, 0xf>(x, 1.0f);
    x *= dpp_mov<0x112, 0xf>(x, 1.0f);
    x *= dpp_mov<0x114, 0xf>(x, 1.0f);
    x *= dpp_mov<0x118, 0xf>(x, 1.0f);
    x *= dpp_mov<0x142, 0xa>(x, 1.0f);
    x *= dpp_mov<0x143, 0xc>(x, 1.0f);
    return x;
}

__device__ __forceinline__ float wave_shr1(float x, float oldv) {
    return dpp_mov<0x138, 0xf>(x, oldv);  // wf_sr1
}

// wave-local LDS fence: all of this wave's outstanding ds ops complete.
__device__ __forceinline__ void lds_fence() {
    __builtin_amdgcn_wave_barrier();
    __asm__ volatile("s_waitcnt lgkmcnt(0)" ::: "memory");
    __builtin_amdgcn_wave_barrier();
}

__global__ __launch_bounds__(256)
void nerf_render_kernel(const float* __restrict__ rays_o,
                        const float* __restrict__ rays_d,
                        const float* __restrict__ aabb,
                        const float* __restrict__ weights,   // [N, 64]
                        const float* __restrict__ sigmas,    // [N, 128]
                        const float* __restrict__ rgbs,      // [N, 128, 3]
                        float* __restrict__ out)             // [N, 388]
{
    const int lane = threadIdx.x & 63;
    const int wid  = threadIdx.x >> 6;
    const int ray  = blockIdx.x * kWavesPerBlock + wid;

    __shared__ float s_mem[kWavesPerBlock][kWaveLds];
    float* zrow  = &s_mem[wid][0];
    float* stage = &s_mem[wid][kZPad];

    // ---- issue all global loads up front (consume order: weights first) ----
    const float wraw = weights[(size_t)ray * kT0 + lane];
    const float2 sg  = *(const float2*)(sigmas + (size_t)ray * kTF + 2 * lane);
    // rgb row: 384 floats. COALESCED: instr k loads floats [2*lane + 128k, +1]
    const float* rb = rgbs + (size_t)ray * (kTF * 3);
    const float2 g0 = *(const float2*)(rb + 2 * lane + 0);     // 512 B contiguous
    const float2 g1 = *(const float2*)(rb + 2 * lane + 128);
    const float2 g2 = *(const float2*)(rb + 2 * lane + 256);

    const float ox = rays_o[ray * 3 + 0], oy = rays_o[ray * 3 + 1], ozr = rays_o[ray * 3 + 2];
    const float dx = rays_d[ray * 3 + 0], dy = rays_d[ray * 3 + 1], dzr = rays_d[ray * 3 + 2];

    // ---- ray-AABB near/far ----
    float near, far;
    {
        const float rx = __builtin_amdgcn_rcpf(dx + 1e-15f);
        const float ry = __builtin_amdgcn_rcpf(dy + 1e-15f);
        const float rz = __builtin_amdgcn_rcpf(dzr + 1e-15f);
        const float t0x = (aabb[0] - ox) * rx, t1x = (aabb[3] - ox) * rx;
        const float t0y = (aabb[1] - oy) * ry, t1y = (aabb[4] - oy) * ry;
        const float t0z = (aabb[2] - ozr) * rz, t1z = (aabb[5] - ozr) * rz;
        near = fmaxf(fmaxf(fminf(t0x, t1x), fminf(t0y, t1y)), fminf(t0z, t1z));
        far  = fminf(fminf(fmaxf(t0x, t1x), fmaxf(t0y, t1y)), fmaxf(t0z, t1z));
        if (far < near) { near = 1e9f; far = 1e9f; }
        near = fmaxf(near, 0.05f);
    }
    const float range = far - near;

    // ---- CDF inclusive scan over coarse weights (DPP) ----
    const float scan  = wave_iscan_add(wraw + 0.01f);
    const float total = __int_as_float(__builtin_amdgcn_readlane(__float_as_int(scan), 63));
    const float c_hi  = fminf(scan * __builtin_amdgcn_rcpf(total), 1.0f); // cdf[lane+1]
    const float c_lo  = wave_shr1(c_hi, 0.0f);                            // cdf[lane]

    // ---- interval-owner scatter of the 129 fine bin edges ----
    {
        const float b_lo = near + range * ((float)lane * (1.0f / kT0));
        const float bw = range * (1.0f / kT0);
        int j_start = (int)ceilf(fmaf(129.0f, c_lo, -0.5f));
        int j_end   = (int)ceilf(fmaf(129.0f, c_hi, -0.5f));
        j_start = j_start < 0 ? 0 : j_start;
        j_end   = j_end > (kTF + 1) ? (kTF + 1) : j_end;
        const float rdenom = __builtin_amdgcn_rcpf(c_hi - c_lo);
        float fj = (float)j_start + 0.5f;
        for (int j = j_start; j < j_end; ++j, fj += 1.0f) {
            float t = (fj * (1.0f / 129.0f) - c_lo) * rdenom;
            t = fminf(fmaxf(t, 0.0f), 1.0f);
            zrow[j] = fmaf(t, bw, b_lo);
        }
    }

    // ---- stage rgb into LDS (coalesced-load lane order -> linear) ----
    // (placed after scatter so the rgb loads had the scan+scatter to land)
    *(float2*)&stage[2 * lane + 0]   = g0;
    *(float2*)&stage[2 * lane + 128] = g1;
    *(float2*)&stage[2 * lane + 256] = g2;

    lds_fence();   // zedge writes + rgb stage writes drained (wave-local)

    // ---- per-lane fine samples 2*lane, 2*lane+1 ----
    const float2 ze01 = *(const float2*)&zrow[2 * lane];   // 8B-aligned
    const float  ze2  = zrow[2 * lane + 2];
    // per-lane rgb: floats 6*lane .. 6*lane+5 (8B-aligned ds_read_b64 x3)
    const float2 rgA = *(const float2*)&stage[6 * lane + 0];   // r0 g0
    const float2 rgB = *(const float2*)&stage[6 * lane + 2];   // b0 r1
    const float2 rgC = *(const float2*)&stage[6 * lane + 4];   // g1 b1

    const float d0 = ze01.y - ze01.x, d1 = ze2 - ze01.y;
    const float z0 = 0.5f * (ze01.x + ze01.y), z1 = 0.5f * (ze01.y + ze2);

    const float e0 = __expf(-sg.x * d0);
    const float e1 = __expf(-sg.y * d1);
    const float a0 = 1.0f - e0, a1 = 1.0f - e1;
    const float f0 = e0 + 1e-10f;
    const float f1 = e1 + 1e-10f;

    // ---- transmittance: wave64 product scan + exact exclusive shift ----
    const float ps   = wave_iscan_mul(f0 * f1);
    const float excl = wave_shr1(ps, 1.0f);
    const float w0 = a0 * excl;
    const float w1 = a1 * excl * f0;

    // ---- image/depth: 4 interleaved DPP scan-reductions; lane 63 = totals ----
    float vr = wave_iscan_add(w0 * rgA.x + w1 * rgB.y);
    float vg = wave_iscan_add(w0 * rgA.y + w1 * rgC.x);
    float vb = wave_iscan_add(w0 * rgB.x + w1 * rgC.y);
    float vd = wave_iscan_add(w0 * z0 + w1 * z1);

    // ---- contraction (branchless): floats 6*lane..6*lane+5 of xyz block ----
    float oxyz[6];
    #pragma unroll
    for (int s = 0; s < 2; ++s) {
        const float z = s ? z1 : z0;
        float px = ox  + dx  * z;
        float py = oy  + dy  * z;
        float pz = ozr + dzr * z;
        const float ax = fabsf(px), ay = fabsf(py), az = fabsf(pz);
        float mag; int idx;
        if (ax >= ay && ax >= az) { mag = ax; idx = 0; }
        else if (ay >= az)        { mag = ay; idx = 1; }
        else                      { mag = az; idx = 2; }
        const float inv    = __builtin_amdgcn_rcpf(mag);
        const bool  inside = mag < 1.0f;
        const float s_oth  = inside ? 1.0f : inv;
        const float s_max  = inside ? 1.0f : (2.0f - inv) * inv;
        oxyz[3 * s + 0] = px * ((idx == 0) ? s_max : s_oth);
        oxyz[3 * s + 1] = py * ((idx == 1) ? s_max : s_oth);
        oxyz[3 * s + 2] = pz * ((idx == 2) ? s_max : s_oth);
    }

    lds_fence();   // WAR: rgb stage reads complete before overwrite

    // ---- stage xyz (24 B/lane) then 3 coalesced 512 B global stores ----
    *(float2*)&stage[6 * lane + 0] = make_float2(oxyz[0], oxyz[1]);
    *(float2*)&stage[6 * lane + 2] = make_float2(oxyz[2], oxyz[3]);
    *(float2*)&stage[6 * lane + 4] = make_float2(oxyz[4], oxyz[5]);

    lds_fence();   // stage writes drained before re-read

    float* orow = out + (size_t)ray * (4 + kTF * 3);   // 1552 B rows, 16B-aligned
    if (lane == 63) {
        *(float4*)orow = make_float4(vr, vg, vb, vd);
    }
    // instr k stores floats [4 + 2*lane + 128k, +1] -> contiguous 512 B
    *(float2*)(orow + 4 + 2 * lane + 0)   = *(const float2*)&stage[2 * lane + 0];
    *(float2*)(orow + 4 + 2 * lane + 128) = *(const float2*)&stage[2 * lane + 128];
    *(float2*)(orow + 4 + 2 * lane + 256) = *(const float2*)&stage[2 * lane + 256];
}

extern "C" void kernel_launch(void* const* d_in, const int* in_sizes, int n_in,
                              void* d_out, int out_size, void* d_ws, size_t ws_size,
                              hipStream_t stream) {
    const float* rays_o  = (const float*)d_in[0];
    const float* rays_d  = (const float*)d_in[1];
    const float* aabb    = (const float*)d_in[2];
    const float* weights = (const float*)d_in[3];
    const float* sigmas  = (const float*)d_in[4];
    const float* rgbs    = (const float*)d_in[5];
    float* out           = (float*)d_out;

    const int N = in_sizes[0] / 3;   // rays_o is [N,3]
    const int blocks = N / kWavesPerBlock;
    nerf_render_kernel<<<blocks, 256, 0, stream>>>(rays_o, rays_d, aabb, weights, sigmas, rgbs, out);
}